// Round 1
// baseline (7250.955 us; speedup 1.0000x reference)
//
#include <hip/hip_runtime.h>

#define NN 100000
#define NE 3200000

// ---------------- CSR build ----------------
__global__ __launch_bounds__(256) void k_deg(const int* __restrict__ col, int* __restrict__ deg) {
    int e = blockIdx.x * 256 + threadIdx.x;
    if (e < NE) atomicAdd(&deg[col[e]], 1);
}

__global__ __launch_bounds__(256) void k_bsum(const int* __restrict__ deg, int* __restrict__ bsum) {
    __shared__ int s[256];
    int t = threadIdx.x, i = blockIdx.x * 256 + t;
    s[t] = (i < NN) ? deg[i] : 0;
    __syncthreads();
    for (int st = 128; st > 0; st >>= 1) {
        if (t < st) s[t] += s[t + st];
        __syncthreads();
    }
    if (t == 0) bsum[blockIdx.x] = s[0];
}

__global__ __launch_bounds__(512) void k_scanb(int* __restrict__ bsum, int nb) {
    __shared__ int s[512];
    int t = threadIdx.x;
    s[t] = (t < nb) ? bsum[t] : 0;
    __syncthreads();
    for (int off = 1; off < 512; off <<= 1) {
        int v = (t >= off) ? s[t - off] : 0;
        __syncthreads();
        s[t] += v;
        __syncthreads();
    }
    if (t < nb) bsum[t] = (t == 0) ? 0 : s[t - 1];
}

__global__ __launch_bounds__(256) void k_colptr(const int* __restrict__ deg, const int* __restrict__ bsum,
                                                int* __restrict__ colptr) {
    __shared__ int s[256];
    int t = threadIdx.x, i = blockIdx.x * 256 + t;
    int v = (i < NN) ? deg[i] : 0;
    s[t] = v;
    __syncthreads();
    for (int off = 1; off < 256; off <<= 1) {
        int u = (t >= off) ? s[t - off] : 0;
        __syncthreads();
        s[t] += u;
        __syncthreads();
    }
    if (i <= NN) colptr[i] = bsum[blockIdx.x] + s[t] - v;   // exclusive scan
}

__global__ __launch_bounds__(256) void k_dis(int* __restrict__ degdis) {
    int i = blockIdx.x * 256 + threadIdx.x;
    if (i < NN) {
        int d = degdis[i];
        ((float*)degdis)[i] = 1.0f / sqrtf((float)(d + 1));  // +1 self loop
    }
}

__global__ __launch_bounds__(256) void k_scatter(const int* __restrict__ ei, const int* __restrict__ colptr,
                                                 int* __restrict__ cursor, int* __restrict__ csr_row) {
    int e = blockIdx.x * 256 + threadIdx.x;
    if (e < NE) {
        int c = ei[NE + e], r = ei[e];
        int pos = colptr[c] + atomicAdd(&cursor[c], 1);
        csr_row[pos] = r;
    }
}

// ---------------- x0 = mynorm(relu(x@W1^T+b1)); out = b32 + x0 @ W32[:, :32]^T; ring0 = mynorm(x0)
__global__ __launch_bounds__(256) void k_x0(const float* __restrict__ x, const float* __restrict__ W1,
                                            const float* __restrict__ b1, const float* __restrict__ W32,
                                            const float* __restrict__ b32, float* __restrict__ h0,
                                            float* __restrict__ ring0, float* __restrict__ out) {
    __shared__ float sW1[32 * 128];
    __shared__ float sW32[64 * 32];
    __shared__ float sb1[32], sb32[64];
    int t = threadIdx.x;
    for (int i = t; i < 4096; i += 256) sW1[i] = W1[i];
    for (int i = t; i < 2048; i += 256) sW32[i] = W32[(i >> 5) * 1024 + (i & 31)];
    if (t < 32) sb1[t] = b1[t];
    if (t < 64) sb32[t] = b32[t];
    __syncthreads();
    int node = blockIdx.x * 256 + t;
    if (node >= NN) return;

    float acc[32];
#pragma unroll
    for (int c = 0; c < 32; c++) acc[c] = sb1[c];
    const float4* xr4 = (const float4*)(x + (long)node * 128);
    for (int q = 0; q < 32; q++) {
        float4 xv = xr4[q];
#pragma unroll
        for (int c = 0; c < 32; c++) {
            acc[c] += xv.x * sW1[c * 128 + q * 4] + xv.y * sW1[c * 128 + q * 4 + 1] +
                      xv.z * sW1[c * 128 + q * 4 + 2] + xv.w * sW1[c * 128 + q * 4 + 3];
        }
    }
    // relu + mynorm
    float mn = 1e30f, mx = -1e30f;
#pragma unroll
    for (int c = 0; c < 32; c++) {
        acc[c] = fmaxf(acc[c], 0.f);
        mn = fminf(mn, acc[c]);
        mx = fmaxf(mx, acc[c]);
    }
    float inv = 2.f / (mx - mn + 1e-8f);
#pragma unroll
    for (int c = 0; c < 32; c++) acc[c] = inv * (acc[c] - mn) - 1.f;  // x0
    // store h0 (float4)
    float4* hr = (float4*)(h0 + (long)node * 32);
#pragma unroll
    for (int q = 0; q < 8; q++) hr[q] = make_float4(acc[4 * q], acc[4 * q + 1], acc[4 * q + 2], acc[4 * q + 3]);
    // m0 = mynorm(x0)
    float mn2 = 1e30f, mx2 = -1e30f;
#pragma unroll
    for (int c = 0; c < 32; c++) {
        mn2 = fminf(mn2, acc[c]);
        mx2 = fmaxf(mx2, acc[c]);
    }
    float inv2 = 2.f / (mx2 - mn2 + 1e-8f);
    float4* rr = (float4*)(ring0 + (long)node * 32);
#pragma unroll
    for (int q = 0; q < 8; q++)
        rr[q] = make_float4(inv2 * (acc[4 * q] - mn2) - 1.f, inv2 * (acc[4 * q + 1] - mn2) - 1.f,
                            inv2 * (acc[4 * q + 2] - mn2) - 1.f, inv2 * (acc[4 * q + 3] - mn2) - 1.f);
    // out init: b32 + x0 @ W32_0^T
    float* orow = out + (long)node * 64;
    for (int o = 0; o < 64; o++) {
        float a = sb32[o];
#pragma unroll
        for (int j = 0; j < 32; j++) a += sW32[o * 32 + j] * acc[j];
        orow[o] = a;
    }
}

// ---------------- one SGConv layer, fully fused ----------------
__global__ __launch_bounds__(256) void k_layer(const float* __restrict__ hin, float* __restrict__ hout,
                                               float* __restrict__ ring, const float* __restrict__ dis,
                                               const int* __restrict__ colptr, const int* __restrict__ csr_row,
                                               const float* __restrict__ Wck, const float* __restrict__ bck,
                                               const float* __restrict__ W32k, float* __restrict__ out,
                                               int rawfeat) {
    int c = threadIdx.x & 31;
    int hw = threadIdx.x >> 5;  // half-wave id 0..7
    int node = blockIdx.x * 8 + hw;
    if (node >= NN) return;

    // per-lane weight rows (L2-hot)
    float wc[32], wa[32], wb[32];
#pragma unroll
    for (int j = 0; j < 32; j++) wc[j] = Wck[c * 32 + j];
#pragma unroll
    for (int j = 0; j < 32; j++) {
        wa[j] = W32k[c * 1024 + j];
        wb[j] = W32k[(c + 32) * 1024 + j];
    }

    int e0 = colptr[node], e1 = colptr[node + 1];
    float di = dis[node];
    float g = di * hin[(long)node * 32 + c];  // self-loop term (x di again at end -> di^2)

    for (int base = e0; base < e1; base += 32) {
        int ee = base + c;
        int r = (ee < e1) ? csr_row[ee] : 0;
        float dv = (ee < e1) ? dis[r] : 0.f;
        int cnt = min(32, e1 - base);
        int j = 0;
        for (; j + 4 <= cnt; j += 4) {
            int r0 = __shfl(r, j, 32), r1 = __shfl(r, j + 1, 32), r2 = __shfl(r, j + 2, 32), r3 = __shfl(r, j + 3, 32);
            float d0 = __shfl(dv, j, 32), d1 = __shfl(dv, j + 1, 32), d2 = __shfl(dv, j + 2, 32),
                  d3 = __shfl(dv, j + 3, 32);
            float h0v = hin[(long)r0 * 32 + c], h1v = hin[(long)r1 * 32 + c];
            float h2v = hin[(long)r2 * 32 + c], h3v = hin[(long)r3 * 32 + c];
            g += d0 * h0v;
            g += d1 * h1v;
            g += d2 * h2v;
            g += d3 * h3v;
        }
        for (; j < cnt; j++) {
            int rj = __shfl(r, j, 32);
            float dj = __shfl(dv, j, 32);
            g += dj * hin[(long)rj * 32 + c];
        }
    }
    g *= di;  // g = (A h)[node][c]

    // y = g @ Wc^T + bc
    float y = bck[c];
#pragma unroll
    for (int j = 0; j < 32; j++) y += wc[j] * __shfl(g, j, 32);
    hout[(long)node * 32 + c] = y;

    // mynorm across the 32 channels (half-wave)
    float mn = y, mx = y;
#pragma unroll
    for (int m = 1; m < 32; m <<= 1) {
        mn = fminf(mn, __shfl_xor(mn, m, 32));
        mx = fmaxf(mx, __shfl_xor(mx, m, 32));
    }
    float mv = 2.f * (y - mn) / (mx - mn + 1e-8f) - 1.f;

    float f = rawfeat ? y : (mv - ring[(long)node * 32 + c]);
    ring[(long)node * 32 + c] = mv;

    // out += f @ W32_k^T  (lane c computes outputs c and c+32)
    float a0 = 0.f, a1 = 0.f;
#pragma unroll
    for (int j = 0; j < 32; j++) {
        float fj = __shfl(f, j, 32);
        a0 += wa[j] * fj;
        a1 += wb[j] * fj;
    }
    out[(long)node * 64 + c] += a0;
    out[(long)node * 64 + 32 + c] += a1;
}

extern "C" void kernel_launch(void* const* d_in, const int* in_sizes, int n_in, void* d_out, int out_size,
                              void* d_ws, size_t ws_size, hipStream_t stream) {
    const float* x = (const float*)d_in[0];
    const int* ei = (const int*)d_in[1];
    const float* W1 = (const float*)d_in[2];
    const float* b1 = (const float*)d_in[3];
    const float* Wc = (const float*)d_in[4];
    const float* bc = (const float*)d_in[5];
    const float* W32 = (const float*)d_in[6];
    const float* b32 = (const float*)d_in[7];
    float* out = (float*)d_out;

    int* deg = (int*)d_ws;            // NN (later reused as dis float)
    int* cursor = deg + NN;           // NN
    int* colptr = cursor + NN;        // NN+1 (padded to 100004)
    int* bsum = colptr + 100004;      // 1024
    int* csr_row = bsum + 1024;       // NE
    float* h0 = (float*)(csr_row + NE);
    float* h1 = h0 + (long)NN * 32;
    float* ring = h1 + (long)NN * 32;  // 2 slots of NN*32
    float* dis = (float*)deg;

    hipMemsetAsync(deg, 0, 2 * NN * sizeof(int), stream);  // deg + cursor
    k_deg<<<(NE + 255) / 256, 256, 0, stream>>>(ei + NE, deg);
    int NB = (NN + 255) / 256;  // 391
    k_bsum<<<NB, 256, 0, stream>>>(deg, bsum);
    k_scanb<<<1, 512, 0, stream>>>(bsum, NB);
    k_colptr<<<NB, 256, 0, stream>>>(deg, bsum, colptr);
    k_dis<<<(NN + 255) / 256, 256, 0, stream>>>(deg);
    k_scatter<<<(NE + 255) / 256, 256, 0, stream>>>(ei, colptr, cursor, csr_row);
    k_x0<<<NB, 256, 0, stream>>>(x, W1, b1, W32, b32, h0, ring, out);

    for (int k = 1; k <= 31; k++) {
        const float* hin = (k & 1) ? h0 : h1;
        float* hout = (k & 1) ? h1 : h0;
        float* ringk = ring + (long)(k & 1) * NN * 32;
        int raw = (k == 1 || k == 16) ? 1 : 0;
        k_layer<<<(NN + 7) / 8, 256, 0, stream>>>(hin, hout, ringk, dis, colptr, csr_row, Wc + (k - 1) * 1024,
                                                  bc + (k - 1) * 32, W32 + 32 * k, out, raw);
    }
}